// Round 4
// baseline (111.495 us; speedup 1.0000x reference)
//
#include <hip/hip_runtime.h>
#include <hip/hip_bf16.h>

#define T_DIM 2048
#define B_DIM 4
#define C_DIM 1024
#define H_DIM 16
#define K_DIM 7
#define HK    112      // H*K

typedef float f32x4 __attribute__((ext_vector_type(4)));
typedef short s16x8 __attribute__((ext_vector_type(8)));

// f32 -> bf16 (round-to-nearest-even), as raw short
__device__ __forceinline__ short f2bf(float f) {
    union { float f; unsigned u; } v; v.f = f;
    return (short)((v.u + 0x7FFFu + ((v.u >> 16) & 1u)) >> 16);
}

// ---------------- Kernel 0: W f32 -> bf16 (112*1024 elems, 56 blocks) -----------
__global__ void k_cvtW(const float* __restrict__ W, short* __restrict__ Wb) {
    const int i = ((int)blockIdx.x * 256 + (int)threadIdx.x) * 8;
    f32x4 a = *(const f32x4*)(W + i);
    f32x4 b = *(const f32x4*)(W + i + 4);
    s16x8 o;
    o[0] = f2bf(a[0]); o[1] = f2bf(a[1]); o[2] = f2bf(a[2]); o[3] = f2bf(a[3]);
    o[4] = f2bf(b[0]); o[5] = f2bf(b[1]); o[6] = f2bf(b[2]); o[7] = f2bf(b[3]);
    *(s16x8*)(Wb + i) = o;
}

// ---------------- Fused: logits GEMM + softmax + causal dynamic conv ------------
// Block = 16 flat rows of (T*B, C) = 4 timesteps x 4 batches. 256 threads.
// Phase 1: bf16 MFMA GEMM, 4 waves split K (8 k-blocks of 32 each), B-frags
//          straight from global (L2-resident Wb).   [verbatim round-2 k_logits]
// Phase 2: combine K-partials in LDS + softmax(K=7) -> smw (f32, block-local).
// Phase 3: conv via rv[10] pre-loaded taps, all static indexing (no rolling
//          register shift, no cross-iteration state).
__global__ __launch_bounds__(256) void k_fused(const float* __restrict__ x,
                                               const short* __restrict__ Wb,
                                               const float* __restrict__ bias,
                                               float* __restrict__ out) {
    __shared__ float sm[4][16][113];
    __shared__ float smw[16][HK];

    const int tid  = (int)threadIdx.x;
    const int lane = tid & 63;
    const int wid  = tid >> 6;
    const int m0   = (int)blockIdx.x * 16;     // first flat row
    const int t0   = (int)blockIdx.x * 4;      // first timestep

    // ---- Phase 1: GEMM (round-2 verified structure, no extra pragmas) ----
    const int cl   = lane & 15;                // A row in tile / B row in n-tile
    const int koff = (lane >> 4) * 8;          // elem offset of lane's 8-elem chunk

    const float* aptr = x  + (size_t)(m0 + cl) * C_DIM + koff;
    const short* bptr = Wb + (size_t)cl * C_DIM + koff;

    f32x4 acc[K_DIM];
    #pragma unroll
    for (int n = 0; n < K_DIM; ++n) acc[n] = (f32x4){0.f, 0.f, 0.f, 0.f};

    for (int q = 0; q < 8; ++q) {
        const int kb = wid * 8 + q;            // this wave's k-block
        f32x4 a0 = *(const f32x4*)(aptr + kb * 32);
        f32x4 a1 = *(const f32x4*)(aptr + kb * 32 + 4);
        s16x8 afr;
        afr[0] = f2bf(a0[0]); afr[1] = f2bf(a0[1]); afr[2] = f2bf(a0[2]); afr[3] = f2bf(a0[3]);
        afr[4] = f2bf(a1[0]); afr[5] = f2bf(a1[1]); afr[6] = f2bf(a1[2]); afr[7] = f2bf(a1[3]);
        #pragma unroll
        for (int nt = 0; nt < K_DIM; ++nt) {
            s16x8 bf = *(const s16x8*)(bptr + nt * 16 * C_DIM + kb * 32);
            acc[nt] = __builtin_amdgcn_mfma_f32_16x16x32_bf16(afr, bf, acc[nt], 0, 0, 0);
        }
    }

    // D layout: col=lane&15, row=(lane>>4)*4 + reg  [m89]
    const int r0 = (lane >> 4) * 4;
    #pragma unroll
    for (int nt = 0; nt < K_DIM; ++nt)
        #pragma unroll
        for (int j = 0; j < 4; ++j)
            sm[wid][r0 + j][nt * 16 + cl] = acc[nt][j];
    __syncthreads();

    // ---- Phase 2: combine + softmax (256 tasks = 16 rows x 16 heads) ----
    {
        const int r = tid >> 4, h = tid & 15;
        float v[K_DIM];
        float mx = -1e30f;
        #pragma unroll
        for (int k = 0; k < K_DIM; ++k) {
            v[k] = sm[0][r][h * 7 + k] + sm[1][r][h * 7 + k]
                 + sm[2][r][h * 7 + k] + sm[3][r][h * 7 + k];
            mx = fmaxf(mx, v[k]);
        }
        float s = 0.f;
        #pragma unroll
        for (int k = 0; k < K_DIM; ++k) { v[k] = __expf(v[k] - mx); s += v[k]; }
        const float inv = 1.f / s;
        #pragma unroll
        for (int k = 0; k < K_DIM; ++k) smw[r][h * 7 + k] = v[k] * inv;
    }
    __syncthreads();

    // ---- Phase 3: conv, static rv[10] taps (no rolling register state) ----
    const int c4 = tid * 4;
    const int h  = tid >> 4;                   // c4/64
    const f32x4 bias4 = *(const f32x4*)(bias + c4);
    const f32x4 zero4 = {0.f, 0.f, 0.f, 0.f};

    #pragma unroll
    for (int b = 0; b < B_DIM; ++b) {
        f32x4 rv[10];                          // x[t0-6+j] for j=0..9, this batch
        #pragma unroll
        for (int j = 0; j < 10; ++j) {
            const int t = t0 - 6 + j;
            rv[j] = (t >= 0)
                  ? *(const f32x4*)(x + (size_t)(t * B_DIM + b) * C_DIM + c4)
                  : zero4;
        }
        #pragma unroll
        for (int tt = 0; tt < 4; ++tt) {
            const float* wr = &smw[tt * 4 + b][h * 7];   // weights for flat row
            f32x4 o = bias4;
            o += rv[tt + 0] * wr[0];
            o += rv[tt + 1] * wr[1];
            o += rv[tt + 2] * wr[2];
            o += rv[tt + 3] * wr[3];
            o += rv[tt + 4] * wr[4];
            o += rv[tt + 5] * wr[5];
            o += rv[tt + 6] * wr[6];
            *(f32x4*)(out + (size_t)((t0 + tt) * B_DIM + b) * C_DIM + c4) = o;
        }
    }
}

extern "C" void kernel_launch(void* const* d_in, const int* in_sizes, int n_in,
                              void* d_out, int out_size, void* d_ws, size_t ws_size,
                              hipStream_t stream) {
    const float* x    = (const float*)d_in[0];
    const float* W    = (const float*)d_in[1];
    const float* bias = (const float*)d_in[2];
    float* out = (float*)d_out;
    short* Wb  = (short*)d_ws;                 // 229 KB bf16 W

    k_cvtW <<<56, 256, 0, stream>>>(W, Wb);
    k_fused<<<(T_DIM * B_DIM) / 16, 256, 0, stream>>>(x, Wb, bias, out);
}

// Round 6
// 108.256 us; speedup vs baseline: 1.0299x; 1.0299x over previous
//
#include <hip/hip_runtime.h>
#include <hip/hip_bf16.h>

#define T_DIM 2048
#define B_DIM 4
#define C_DIM 1024
#define H_DIM 16
#define K_DIM 7
#define HK    112      // H*K

typedef float f32x4 __attribute__((ext_vector_type(4)));
typedef short s16x8 __attribute__((ext_vector_type(8)));

// f32 -> bf16 (round-to-nearest-even), as raw short
__device__ __forceinline__ short f2bf(float f) {
    union { float f; unsigned u; } v; v.f = f;
    return (short)((v.u + 0x7FFFu + ((v.u >> 16) & 1u)) >> 16);
}

// ---------------- Kernel 0: W f32 -> bf16 (112*1024 elems, 56 blocks) -----------
__global__ void k_cvtW(const float* __restrict__ W, short* __restrict__ Wb) {
    const int i = ((int)blockIdx.x * 256 + (int)threadIdx.x) * 8;
    f32x4 a = *(const f32x4*)(W + i);
    f32x4 b = *(const f32x4*)(W + i + 4);
    s16x8 o;
    o[0] = f2bf(a[0]); o[1] = f2bf(a[1]); o[2] = f2bf(a[2]); o[3] = f2bf(a[3]);
    o[4] = f2bf(b[0]); o[5] = f2bf(b[1]); o[6] = f2bf(b[2]); o[7] = f2bf(b[3]);
    *(s16x8*)(Wb + i) = o;
}

// ---- Fused: logits GEMM + softmax + causal conv.  R4-passing structure with ----
// ---- 8-way K-split (512 thr) and prefetched conv taps.                      ----
// Block = 16 flat rows = 4 timesteps x 4 batches. 8 waves, wave w = k-blocks
// w*4..w*4+3 over all 7 n-tiles. Grid 512 -> 2 blocks/CU -> 16 waves/CU.
__global__ __launch_bounds__(512, 4) void k_fused(const float* __restrict__ x,
                                                  const short* __restrict__ Wb,
                                                  const float* __restrict__ bias,
                                                  float* __restrict__ out) {
    __shared__ float sm[8][16][113];
    __shared__ float smw[16][HK];

    const int tid  = (int)threadIdx.x;
    const int lane = tid & 63;
    const int wid  = tid >> 6;                 // 0..7
    const int m0   = (int)blockIdx.x * 16;     // first flat row
    const int t0   = (int)blockIdx.x * 4;      // first timestep

    // ---- Phase-3 prefetch: first batch's taps, issued before the GEMM so the
    //      HBM latency hides under phase 1 (T14 issue-early / use-late).
    const int cid = tid & 255;                 // channel quad 0..255
    const int bs2 = (tid >> 8) * 2;            // batch pair base: 0 or 2
    const int c4  = cid * 4;
    const int h   = cid >> 4;                  // c4/64
    const f32x4 zero4 = {0.f, 0.f, 0.f, 0.f};

    f32x4 rv0[10];                             // x[t0-6+j], batch bs2
    #pragma unroll
    for (int j = 0; j < 10; ++j) {
        const int t = t0 - 6 + j;
        rv0[j] = (t >= 0)
               ? *(const f32x4*)(x + (size_t)(t * B_DIM + bs2) * C_DIM + c4)
               : zero4;
    }

    // ---- Phase 1: GEMM (R4 structure; 8-way K-split) ----
    const int cl   = lane & 15;                // A row in tile / B row in n-tile
    const int koff = (lane >> 4) * 8;          // lane's 8-elem k-chunk

    const float* aptr = x  + (size_t)(m0 + cl) * C_DIM + koff;
    const short* bptr = Wb + (size_t)cl * C_DIM + koff;

    f32x4 acc[K_DIM];
    #pragma unroll
    for (int n = 0; n < K_DIM; ++n) acc[n] = (f32x4){0.f, 0.f, 0.f, 0.f};

    for (int q = 0; q < 4; ++q) {
        const int kb32 = (wid * 4 + q) * 32;   // this wave's k-block offset (elems)
        f32x4 a0 = *(const f32x4*)(aptr + kb32);
        f32x4 a1 = *(const f32x4*)(aptr + kb32 + 4);
        s16x8 afr;
        afr[0] = f2bf(a0[0]); afr[1] = f2bf(a0[1]); afr[2] = f2bf(a0[2]); afr[3] = f2bf(a0[3]);
        afr[4] = f2bf(a1[0]); afr[5] = f2bf(a1[1]); afr[6] = f2bf(a1[2]); afr[7] = f2bf(a1[3]);
        #pragma unroll
        for (int nt = 0; nt < K_DIM; ++nt) {
            s16x8 bf = *(const s16x8*)(bptr + nt * 16 * C_DIM + kb32);
            acc[nt] = __builtin_amdgcn_mfma_f32_16x16x32_bf16(afr, bf, acc[nt], 0, 0, 0);
        }
    }

    // D layout: col=lane&15, row=(lane>>4)*4 + reg  [m89]
    const int r0 = (lane >> 4) * 4;
    #pragma unroll
    for (int nt = 0; nt < K_DIM; ++nt)
        #pragma unroll
        for (int j = 0; j < 4; ++j)
            sm[wid][r0 + j][nt * 16 + cl] = acc[nt][j];
    __syncthreads();

    // ---- Phase 2: combine 8 K-partials + softmax (256 tasks = 16 rows x 16 heads) ----
    if (tid < 256) {
        const int r = tid >> 4, hh = tid & 15;
        float v[K_DIM];
        float mx = -1e30f;
        #pragma unroll
        for (int k = 0; k < K_DIM; ++k) {
            const int cc = hh * 7 + k;
            v[k] = ((sm[0][r][cc] + sm[1][r][cc]) + (sm[2][r][cc] + sm[3][r][cc]))
                 + ((sm[4][r][cc] + sm[5][r][cc]) + (sm[6][r][cc] + sm[7][r][cc]));
            mx = fmaxf(mx, v[k]);
        }
        float s = 0.f;
        #pragma unroll
        for (int k = 0; k < K_DIM; ++k) { v[k] = __expf(v[k] - mx); s += v[k]; }
        const float inv = 1.f / s;
        #pragma unroll
        for (int k = 0; k < K_DIM; ++k) smw[r][hh * 7 + k] = v[k] * inv;
    }
    __syncthreads();

    // ---- Phase 3: conv. Thread = (channel-quad, batch-pair); static rv taps. ----
    const f32x4 bias4 = *(const f32x4*)(bias + c4);

    // batch bs2 (taps prefetched); issue batch bs2+1 loads, then compute bs2.
    f32x4 rv1[10];
    #pragma unroll
    for (int j = 0; j < 10; ++j) {
        const int t = t0 - 6 + j;
        rv1[j] = (t >= 0)
               ? *(const f32x4*)(x + (size_t)(t * B_DIM + bs2 + 1) * C_DIM + c4)
               : zero4;
    }

    #pragma unroll
    for (int tt = 0; tt < 4; ++tt) {
        const float* wr = &smw[tt * 4 + bs2][h * 7];
        f32x4 o = bias4;
        o += rv0[tt + 0] * wr[0];
        o += rv0[tt + 1] * wr[1];
        o += rv0[tt + 2] * wr[2];
        o += rv0[tt + 3] * wr[3];
        o += rv0[tt + 4] * wr[4];
        o += rv0[tt + 5] * wr[5];
        o += rv0[tt + 6] * wr[6];
        *(f32x4*)(out + (size_t)((t0 + tt) * B_DIM + bs2) * C_DIM + c4) = o;
    }
    #pragma unroll
    for (int tt = 0; tt < 4; ++tt) {
        const float* wr = &smw[tt * 4 + bs2 + 1][h * 7];
        f32x4 o = bias4;
        o += rv1[tt + 0] * wr[0];
        o += rv1[tt + 1] * wr[1];
        o += rv1[tt + 2] * wr[2];
        o += rv1[tt + 3] * wr[3];
        o += rv1[tt + 4] * wr[4];
        o += rv1[tt + 5] * wr[5];
        o += rv1[tt + 6] * wr[6];
        *(f32x4*)(out + (size_t)((t0 + tt) * B_DIM + bs2 + 1) * C_DIM + c4) = o;
    }
}

extern "C" void kernel_launch(void* const* d_in, const int* in_sizes, int n_in,
                              void* d_out, int out_size, void* d_ws, size_t ws_size,
                              hipStream_t stream) {
    const float* x    = (const float*)d_in[0];
    const float* W    = (const float*)d_in[1];
    const float* bias = (const float*)d_in[2];
    float* out = (float*)d_out;
    short* Wb  = (short*)d_ws;                 // 229 KB bf16 W

    k_cvtW <<<56, 256, 0, stream>>>(W, Wb);
    k_fused<<<(T_DIM * B_DIM) / 16, 512, 0, stream>>>(x, Wb, bias, out);
}